// Round 2
// baseline (522.807 us; speedup 1.0000x reference)
//
#include <hip/hip_runtime.h>
#include <hip/hip_bf16.h>

#define HW_ 36864
#define W_ 192
#define H_ 192
#define NPIX_ 73728
#define TWO_PI_F 6.283185307179586f

__device__ __constant__ float DT_G[12] = {
    1.0f, 2.154434690031884f, 4.641588833612779f, 10.0f,
    21.54434690031884f, 46.41588833612779f, 100.0f, 215.4434690031884f,
    464.1588833612779f, 1000.0f, 2154.434690031884f, 4641.588833612779f};

__device__ __forceinline__ float bfu2f(unsigned short u) {
    return __uint_as_float(((unsigned int)u) << 16);
}
__device__ __forceinline__ unsigned short f2bfbits(float f) {
    __hip_bfloat16 h = __float2bfloat16(f);
    unsigned short u;
    __builtin_memcpy(&u, &h, 2);
    return u;
}
__device__ __forceinline__ float to_f(float v) { return v; }
__device__ __forceinline__ float to_f(unsigned short v) { return bfu2f(v); }

struct __align__(16) Smem {
    float wrpl[2][192];   // gathered y + pb, [slot][c*4+v]
    float xinl[2][48];    // x + point-PE
    float outt[128 * 33]; // out tile [ch][32px], padded
    float pbl[192];       // window position bias [v][c]
    float wl[864];        // conv weights
    float offs[32];       // per-pixel offsets for this block
    unsigned short qwl[6144], kwl[6144], vwl[6144];
};

// stage 48x128 projection weights into LDS as bf16 bits
__device__ __forceinline__ void stage_w(unsigned short* dst, const unsigned short* src, int tid) {
    for (int i = tid; i < 3072; i += 256)
        ((unsigned int*)dst)[i] = ((const unsigned int*)src)[i];
}
__device__ __forceinline__ void stage_w(unsigned short* dst, const float* src, int tid) {
    for (int i = tid; i < 6144; i += 256) dst[i] = f2bfbits(src[i]);
}

// final coalesced store of one (channel, half-row): 16 consecutive pixels
__device__ __forceinline__ void store_row(unsigned short* out, size_t base, const float* s) {
    unsigned int pk[8];
#pragma unroll
    for (int i = 0; i < 8; ++i)
        pk[i] = (unsigned int)f2bfbits(s[2 * i]) | ((unsigned int)f2bfbits(s[2 * i + 1]) << 16);
    uint4* d = (uint4*)(out + base);
    d[0] = make_uint4(pk[0], pk[1], pk[2], pk[3]);
    d[1] = make_uint4(pk[4], pk[5], pk[6], pk[7]);
}
__device__ __forceinline__ void store_row(float* out, size_t base, const float* s) {
    float4* d = (float4*)(out + base);
    d[0] = make_float4(s[0], s[1], s[2], s[3]);
    d[1] = make_float4(s[4], s[5], s[6], s[7]);
    d[2] = make_float4(s[8], s[9], s[10], s[11]);
    d[3] = make_float4(s[12], s[13], s[14], s[15]);
}

template <typename T>
__device__ void run_all(Smem& sm,
                        const T* __restrict__ y, const T* __restrict__ x,
                        const T* __restrict__ cw, const T* __restrict__ cb,
                        const T* __restrict__ qw, const T* __restrict__ qb,
                        const T* __restrict__ kw, const T* __restrict__ kb,
                        const T* __restrict__ vw, const T* __restrict__ vb,
                        T* __restrict__ out, int tid, int bx) {
    // ---- stage conv + projection weights ----
    for (int i = tid; i < 864; i += 256) sm.wl[i] = to_f(cw[i]);
    stage_w(sm.qwl, qw, tid);
    stage_w(sm.kwl, kw, tid);
    stage_w(sm.vwl, vw, tid);

    int pix0 = bx * 32;
    int n = pix0 / HW_;
    int rem0 = pix0 - n * HW_;
    int ch = tid & 127;
    int slot = tid >> 7;
    float qb_r = to_f(qb[ch]);
    float kb_r = to_f(kb[ch]);
    float vb_r = to_f(vb[ch]);
    float cb0 = to_f(cb[0]);
    __syncthreads();

    // ---- inline 3x3 conv for this block's 32 pixels (8 threads / pixel) ----
    {
        int px_l = tid >> 3, sub = tid & 7;
        int pix = pix0 + px_l;
        int rem = pix - n * HW_;
        int row = rem / W_;
        int col = rem - row * W_;
        float acc = 0.0f;
#pragma unroll 4
        for (int icl = 0; icl < 12; ++icl) {
            int ic = sub * 12 + icl;
            const T* src = (ic < 48) ? y : x;
            int c = (ic < 48) ? ic : ic - 48;
            size_t base = (size_t)(n * 48 + c) * HW_;
#pragma unroll
            for (int ky = 0; ky < 3; ++ky) {
                int r = row + ky - 1;
                if ((unsigned)r < (unsigned)H_) {
                    size_t rb = base + (size_t)r * W_;
#pragma unroll
                    for (int kx = 0; kx < 3; ++kx) {
                        int cc = col + kx - 1;
                        if ((unsigned)cc < (unsigned)W_)
                            acc += to_f(src[rb + cc]) * sm.wl[ic * 9 + ky * 3 + kx];
                    }
                }
            }
        }
#pragma unroll
        for (int m = 1; m < 8; m <<= 1) acc += __shfl_xor(acc, m);
        if (sub == 0) sm.offs[px_l] = (acc + cb0) * (2.0f / (float)W_);
    }
    __syncthreads();

    // ---- main loop: 16 iterations x 2 pixels ----
    for (int it = 0; it < 16; ++it) {
        for (int e = tid; e < 480; e += 256) {
            if (e < 96) {
                int s = e / 48, c = e - s * 48;
                int p = it * 2 + s;
                int rem = rem0 + p;
                float o = sm.offs[p];
                int col = rem % W_;
                float gx = (float)col + o;
                float fr = gx - floorf(gx);
                float pe;
                if (c < 24) {
                    pe = (c & 1) ? 1.0f : 0.0f; // frac_y == 0: sin(0)/cos(0)
                } else {
                    int cc = c - 24;
                    int j = cc >> 1;
                    float t1 = fr / (2.0f + 1e-6f);
                    float arg = (t1 * TWO_PI_F) / DT_G[j];
                    pe = (cc & 1) ? cosf(arg) : sinf(arg);
                }
                sm.xinl[s][c] = to_f(x[(size_t)(n * 48 + c) * HW_ + rem]) + pe;
            } else {
                int e2 = e - 96;
                int s = e2 / 192, r = e2 - s * 192;
                int c = r >> 2, v = r & 3;
                int p = it * 2 + s;
                int rem = rem0 + p;
                int row = rem / W_;
                int col = rem - row * W_;
                float o = sm.offs[p];
                float gx = (float)col + o;
                float fx = floorf(gx);
                int dy = v >> 1, dx = v & 1;
                float gy = (float)(row + dy);
                float gxx = fx + (float)dx;
                int rr = (int)fminf(fmaxf(gy, 0.0f), 191.0f);
                int ccx = (int)fminf(fmaxf(gxx, 0.0f), 191.0f);
                float val = to_f(y[(size_t)(n * 48 + c) * HW_ + rr * W_ + ccx]);
                sm.wrpl[s][c * 4 + v] = val + sm.pbl[v * 48 + c];
            }
        }
        __syncthreads();

        float q = qb_r;
        float k0 = kb_r, k1 = kb_r, k2 = kb_r, k3 = kb_r;
        float v0 = vb_r, v1 = vb_r, v2 = vb_r, v3 = vb_r;
        const float* xr = sm.xinl[slot];
        const float* wr = sm.wrpl[slot];
#pragma unroll 8
        for (int c = 0; c < 48; ++c) {
            float xv = xr[c];
            float wq = bfu2f(sm.qwl[c * 128 + ch]);
            float wk = bfu2f(sm.kwl[c * 128 + ch]);
            float wvv = bfu2f(sm.vwl[c * 128 + ch]);
            q += xv * wq;
            float4 g = *((const float4*)(wr + c * 4));
            k0 += g.x * wk; k1 += g.y * wk; k2 += g.z * wk; k3 += g.w * wk;
            v0 += g.x * wvv; v1 += g.y * wvv; v2 += g.z * wvv; v3 += g.w * wvv;
        }

        float l0 = q * k0, l1 = q * k1, l2 = q * k2, l3 = q * k3;
#pragma unroll
        for (int m = 1; m < 16; m <<= 1) {
            l0 += __shfl_xor(l0, m);
            l1 += __shfl_xor(l1, m);
            l2 += __shfl_xor(l2, m);
            l3 += __shfl_xor(l3, m);
        }
        const float SC = 0.25f; // HEAD_DIM^-0.5
        l0 *= SC; l1 *= SC; l2 *= SC; l3 *= SC;
        float mx = fmaxf(fmaxf(l0, l1), fmaxf(l2, l3));
        float e0 = expf(l0 - mx), e1 = expf(l1 - mx);
        float e2 = expf(l2 - mx), e3 = expf(l3 - mx);
        float den = e0 + e1 + e2 + e3;
        float o = (e0 * v0 + e1 * v1 + e2 * v2 + e3 * v3) / den;
        sm.outt[ch * 33 + it * 2 + slot] = o;
        __syncthreads();
    }

    // ---- coalesced flush: one 64B line per (channel, half) ----
    {
        int chf = tid >> 1, half = tid & 1;
        size_t base = (size_t)(n * 128 + chf) * HW_ + rem0 + half * 16;
        store_row(out, base, &sm.outt[chf * 33 + half * 16]);
    }
}

__global__ __launch_bounds__(256) void fused_kernel(
    const void* yv, const void* xv, const void* cwv, const void* cbv,
    const void* qwv, const void* qbv, const void* kwv, const void* kbv,
    const void* vwv, const void* vbv, void* outv) {
    __shared__ Smem sm;
    __shared__ int s_wild, s_lowz;
    int tid = threadIdx.x;

    // ---- dtype probe: scan first 32KB of x ----
    if (tid == 0) { s_wild = 0; s_lowz = 0; }
    __syncthreads();
    {
        const unsigned int* xw = (const unsigned int*)xv;
        int wild = 0, lowz = 0;
        for (int i = tid; i < 8192; i += 256) {
            unsigned int u = xw[i];
            unsigned int lo = u & 0xFFFFu, hi = u >> 16;
            unsigned int el = (lo >> 7) & 0xFFu, ml = lo & 0x7Fu;
            unsigned int eh = (hi >> 7) & 0xFFu, mh = hi & 0x7Fu;
            if (el == 0xFFu || (el == 0u && ml != 0u)) wild++;
            if (eh == 0xFFu || (eh == 0u && mh != 0u)) wild++;
            if (lo == 0u) lowz++;
        }
        if (wild) atomicAdd(&s_wild, wild);
        if (lowz) atomicAdd(&s_lowz, lowz);
    }

    // window position bias (dtype-independent)
    if (tid < 192) {
        int v = tid / 48, c = tid - (tid / 48) * 48;
        int iy = v >> 1, ix = v & 1;
        int cc = (c < 24) ? c : c - 24;
        int sel = (c < 24) ? iy : ix;
        float e = sel ? (TWO_PI_F / (1.0f + 1e-6f)) : 0.0f;
        int j = cc >> 1;
        float arg = e / DT_G[j];
        sm.pbl[v * 48 + c] = (cc & 1) ? cosf(arg) : sinf(arg);
    }
    __syncthreads();
    const bool isf32 = (s_wild > 0) || (s_lowz > 4096);

    if (isf32) {
        run_all<float>(sm, (const float*)yv, (const float*)xv,
                       (const float*)cwv, (const float*)cbv,
                       (const float*)qwv, (const float*)qbv,
                       (const float*)kwv, (const float*)kbv,
                       (const float*)vwv, (const float*)vbv,
                       (float*)outv, tid, blockIdx.x);
    } else {
        run_all<unsigned short>(sm, (const unsigned short*)yv, (const unsigned short*)xv,
                                (const unsigned short*)cwv, (const unsigned short*)cbv,
                                (const unsigned short*)qwv, (const unsigned short*)qbv,
                                (const unsigned short*)kwv, (const unsigned short*)kbv,
                                (const unsigned short*)vwv, (const unsigned short*)vbv,
                                (unsigned short*)outv, tid, blockIdx.x);
    }
}

extern "C" void kernel_launch(void* const* d_in, const int* in_sizes, int n_in,
                              void* d_out, int out_size, void* d_ws, size_t ws_size,
                              hipStream_t stream) {
    hipLaunchKernelGGL(fused_kernel, dim3(NPIX_ / 32), dim3(256), 0, stream,
                       d_in[0], d_in[1], d_in[2], d_in[3], d_in[4], d_in[5],
                       d_in[6], d_in[7], d_in[8], d_in[9], d_out);
}

// Round 3
// 256.765 us; speedup vs baseline: 2.0361x; 2.0361x over previous
//
#include <hip/hip_runtime.h>
#include <hip/hip_bf16.h>

#define HW_ 36864
#define W_ 192
#define H_ 192
#define NPIX_ 73728
#define TWO_PI_F 6.283185307179586f

typedef __attribute__((ext_vector_type(8))) short bfrag;
typedef __attribute__((ext_vector_type(4))) float f4;

__device__ __constant__ float DT_G[12] = {
    1.0f, 2.154434690031884f, 4.641588833612779f, 10.0f,
    21.54434690031884f, 46.41588833612779f, 100.0f, 215.4434690031884f,
    464.1588833612779f, 1000.0f, 2154.434690031884f, 4641.588833612779f};

__device__ __forceinline__ unsigned short f2bf(float f) {
    __hip_bfloat16 h = __float2bfloat16(f);
    unsigned short u;
    __builtin_memcpy(&u, &h, 2);
    return u;
}

struct __align__(16) Smem {
    unsigned short A[10 * 1024]; // frag-order A tiles: [0..1]=xin (32 rows), [2..9]=wrp (128 rows)
    float outt[128 * 33];        // out tile [ch][32px], pad 33
    float wl[864];               // conv weights
    float pbl[192];              // window position bias [v][c]
    float offs[32];              // per-pixel offsets
};

// A-frag storage index (u16 units) for (row m in tile, k in 0..63):
//   ks-block (k>>5)*512, then lane = m + 16*((k>>3)&3), elem j = k&7 -> lane*8+j
__device__ __forceinline__ int a_idx(int tile, int m, int k) {
    return tile * 1024 + ((k >> 5) << 9) + (m << 3) + (((k >> 3) & 3) << 7) + (k & 7);
}

// B fragment straight from global f32 weights w[k][128]; k>=48 -> 0
__device__ __forceinline__ bfrag loadB(const float* __restrict__ w, int h, int ks,
                                       int lq, int lg) {
    int n = (h << 4) + lq;
    int k0 = (ks << 5) + (lg << 3);
    bfrag r;
#pragma unroll
    for (int j = 0; j < 8; ++j) {
        int k = k0 + j;
        float f = (k < 48) ? w[k * 128 + n] : 0.0f;
        r[j] = (short)f2bf(f);
    }
    return r;
}

__global__ __launch_bounds__(256, 3) void fused_kernel(
    const float* __restrict__ y, const float* __restrict__ x,
    const float* __restrict__ cw, const float* __restrict__ cb,
    const float* __restrict__ qw, const float* __restrict__ qb,
    const float* __restrict__ kw, const float* __restrict__ kb,
    const float* __restrict__ vw, const float* __restrict__ vb,
    float* __restrict__ out) {
    __shared__ Smem sm;
    int tid = threadIdx.x;
    int pix0 = blockIdx.x * 32;
    int n = pix0 / HW_;
    int rem0 = pix0 - n * HW_;

    // ---- phase 1: conv weights, position bias, zero A ----
    for (int i = tid; i < 864; i += 256) sm.wl[i] = cw[i];
    if (tid < 192) {
        int v = tid / 48, c = tid - (tid / 48) * 48;
        int iy = v >> 1, ix = v & 1;
        int cc = (c < 24) ? c : c - 24;
        int sel = (c < 24) ? iy : ix;
        float e = sel ? (TWO_PI_F / (1.0f + 1e-6f)) : 0.0f;
        int j = cc >> 1;
        float arg = e / DT_G[j];
        sm.pbl[v * 48 + c] = (cc & 1) ? cosf(arg) : sinf(arg);
    }
    for (int i = tid; i < 5120; i += 256) ((unsigned int*)sm.A)[i] = 0u;
    __syncthreads();

    // ---- phase 2: 3x3 conv -> offs[32] (8 threads/pixel) ----
    {
        int px_l = tid >> 3, sub = tid & 7;
        int rem = rem0 + px_l;
        int row = rem / W_;
        int col = rem - row * W_;
        float acc = 0.0f;
#pragma unroll 4
        for (int icl = 0; icl < 12; ++icl) {
            int ic = sub * 12 + icl;
            const float* src = (ic < 48) ? y : x;
            int c = (ic < 48) ? ic : ic - 48;
            size_t base = (size_t)(n * 48 + c) * HW_;
#pragma unroll
            for (int ky = 0; ky < 3; ++ky) {
                int r = row + ky - 1;
                if ((unsigned)r < (unsigned)H_) {
                    size_t rb = base + (size_t)r * W_;
#pragma unroll
                    for (int kx = 0; kx < 3; ++kx) {
                        int ccx = col + kx - 1;
                        if ((unsigned)ccx < (unsigned)W_)
                            acc += src[rb + ccx] * sm.wl[ic * 9 + ky * 3 + kx];
                    }
                }
            }
        }
#pragma unroll
        for (int m = 1; m < 8; m <<= 1) acc += __shfl_xor(acc, m);
        if (sub == 0) sm.offs[px_l] = (acc + cb[0]) * (2.0f / (float)W_);
    }
    __syncthreads();

    // ---- phase 3: stage A operands (bf16, frag order) ----
    // xin: 32px x 48c  (x + point-PE)
    for (int e = tid; e < 1536; e += 256) {
        int c = e >> 5, p = e & 31;
        int rem = rem0 + p;
        float o = sm.offs[p];
        int col = rem % W_;
        float gx = (float)col + o;
        float fr = gx - floorf(gx);
        float pe;
        if (c < 24) {
            pe = (c & 1) ? 1.0f : 0.0f; // frac_y == 0
        } else {
            int cc = c - 24;
            int j = cc >> 1;
            float t1 = fr / (2.0f + 1e-6f);
            float arg = (t1 * TWO_PI_F) / DT_G[j];
            pe = (cc & 1) ? cosf(arg) : sinf(arg);
        }
        float val = x[(size_t)(n * 48 + c) * HW_ + rem] + pe;
        sm.A[a_idx(p >> 4, p & 15, c)] = f2bf(val);
    }
    // wrp: 128 rows (px*4+v) x 48c  (gathered y + window bias)
    for (int e = tid; e < 6144; e += 256) {
        int c = e >> 7, r = e & 127;
        int p = r >> 2, v = r & 3;
        int rem = rem0 + p;
        int row = rem / W_;
        int col = rem - row * W_;
        float o = sm.offs[p];
        float gx = (float)col + o;
        float fx = floorf(gx);
        int dy = v >> 1, dx = v & 1;
        int rr = (int)fminf(fmaxf((float)(row + dy), 0.0f), 191.0f);
        int ccx = (int)fminf(fmaxf(fx + (float)dx, 0.0f), 191.0f);
        float val = y[(size_t)(n * 48 + c) * HW_ + rr * W_ + ccx] + sm.pbl[v * 48 + c];
        sm.A[a_idx(2 + (r >> 4), r & 15, c)] = f2bf(val);
    }
    __syncthreads();

    // ---- phase 4: MFMA projections + register attention ----
    int lane = tid & 63, wid = tid >> 6;
    int lq = lane & 15, lg = lane >> 4;

    bfrag qA[2][2], wA[8][2];
#pragma unroll
    for (int t = 0; t < 2; ++t)
#pragma unroll
        for (int ks = 0; ks < 2; ++ks)
            qA[t][ks] = *(const bfrag*)&sm.A[t * 1024 + ks * 512 + lane * 8];
#pragma unroll
    for (int t = 0; t < 8; ++t)
#pragma unroll
        for (int ks = 0; ks < 2; ++ks)
            wA[t][ks] = *(const bfrag*)&sm.A[(2 + t) * 1024 + ks * 512 + lane * 8];

#pragma unroll
    for (int hh = 0; hh < 2; ++hh) {
        int h = wid * 2 + hh;
        float qbv = qb[(h << 4) + lq];
        float kbv = kb[(h << 4) + lq];
        float vbv = vb[(h << 4) + lq];

        bfrag qB0 = loadB(qw, h, 0, lq, lg), qB1 = loadB(qw, h, 1, lq, lg);
        f4 qacc[2];
#pragma unroll
        for (int t = 0; t < 2; ++t) {
            f4 a = {qbv, qbv, qbv, qbv};
            a = __builtin_amdgcn_mfma_f32_16x16x32_bf16(qA[t][0], qB0, a, 0, 0, 0);
            a = __builtin_amdgcn_mfma_f32_16x16x32_bf16(qA[t][1], qB1, a, 0, 0, 0);
            qacc[t] = a;
        }
        bfrag kB0 = loadB(kw, h, 0, lq, lg), kB1 = loadB(kw, h, 1, lq, lg);
        bfrag vB0 = loadB(vw, h, 0, lq, lg), vB1 = loadB(vw, h, 1, lq, lg);

#pragma unroll
        for (int m = 0; m < 8; ++m) {
            f4 ka = {kbv, kbv, kbv, kbv};
            ka = __builtin_amdgcn_mfma_f32_16x16x32_bf16(wA[m][0], kB0, ka, 0, 0, 0);
            ka = __builtin_amdgcn_mfma_f32_16x16x32_bf16(wA[m][1], kB1, ka, 0, 0, 0);
            f4 va = {vbv, vbv, vbv, vbv};
            va = __builtin_amdgcn_mfma_f32_16x16x32_bf16(wA[m][0], vB0, va, 0, 0, 0);
            va = __builtin_amdgcn_mfma_f32_16x16x32_bf16(wA[m][1], vB1, va, 0, 0, 0);

            // q broadcast: pixel p = 4m+lg lives in qacc[m>>2], reg lg, lane (m&3)*16+lq
            int src = ((m & 3) << 4) | lq;
            f4 qa = qacc[m >> 2];
            float t0 = __shfl(qa.x, src), t1 = __shfl(qa.y, src);
            float t2 = __shfl(qa.z, src), t3 = __shfl(qa.w, src);
            float qv = (lg == 0) ? t0 : (lg == 1) ? t1 : (lg == 2) ? t2 : t3;
            qv *= 0.25f; // HEAD_DIM^-0.5

            float s0 = qv * ka.x, s1 = qv * ka.y, s2 = qv * ka.z, s3 = qv * ka.w;
#pragma unroll
            for (int msk = 1; msk < 16; msk <<= 1) {
                s0 += __shfl_xor(s0, msk);
                s1 += __shfl_xor(s1, msk);
                s2 += __shfl_xor(s2, msk);
                s3 += __shfl_xor(s3, msk);
            }
            float mx = fmaxf(fmaxf(s0, s1), fmaxf(s2, s3));
            float e0 = __expf(s0 - mx), e1 = __expf(s1 - mx);
            float e2 = __expf(s2 - mx), e3 = __expf(s3 - mx);
            float rden = 1.0f / (e0 + e1 + e2 + e3);
            float o = (e0 * va.x + e1 * va.y + e2 * va.z + e3 * va.w) * rden;
            sm.outt[((h << 4) + lq) * 33 + (m << 2) + lg] = o;
        }
    }
    __syncthreads();

    // ---- phase 5: coalesced flush (64B lines per channel-half) ----
    {
        int ch = tid >> 1, half = tid & 1;
        const float* sp = &sm.outt[ch * 33 + half * 16];
        float4* dst = (float4*)(out + (size_t)(n * 128 + ch) * HW_ + rem0 + half * 16);
#pragma unroll
        for (int i = 0; i < 4; ++i)
            dst[i] = make_float4(sp[4 * i], sp[4 * i + 1], sp[4 * i + 2], sp[4 * i + 3]);
    }
}

extern "C" void kernel_launch(void* const* d_in, const int* in_sizes, int n_in,
                              void* d_out, int out_size, void* d_ws, size_t ws_size,
                              hipStream_t stream) {
    hipLaunchKernelGGL(fused_kernel, dim3(NPIX_ / 32), dim3(256), 0, stream,
                       (const float*)d_in[0], (const float*)d_in[1],
                       (const float*)d_in[2], (const float*)d_in[3],
                       (const float*)d_in[4], (const float*)d_in[5],
                       (const float*)d_in[6], (const float*)d_in[7],
                       (const float*)d_in[8], (const float*)d_in[9],
                       (float*)d_out);
}